// Round 5
// baseline (262.828 us; speedup 1.0000x reference)
//
#include <hip/hip_runtime.h>

// Output layout (flat, reference return order), N=64, B=16, D=512:
//   [0,       mapsz)          boundary [B,D,N,N]
//   [mapsz, 2*mapsz)          content  [B,D,N,N]
//   [2*mapsz, 2*mapsz+B*N*N)  mask     [B,1,N,N] (0.0/1.0 f32)
//
// Identities (verified R1-R4): on member lines content[i,j] = max(x[i..j]),
// boundary[i,j] = 0.5*(x[i]+x[j]); diagonal is the len=1 case of both.
//
// R5 = R3 structure (best: 250.3 us) + NONTEMPORAL stores. The output is
// write-once-never-read and immediately follows a 1.075 GB poison fill that
// leaves L2 full of dirty lines; nt stores stream past L2 retention and
// avoid WAW churn with the draining fill. Single-variable experiment.

#define T_PER_WAVE 2   // 8192 tiles / 2 = 4096 waves = 1024 blocks

__global__ __launch_bounds__(256) void sbc_kernel(const float* __restrict__ x,
                                                  float* __restrict__ out,
                                                  size_t mapsz) {
    const int lane = threadIdx.x & 63;               // column j
    const int wid  = blockIdx.x * 4 + (threadIdx.x >> 6);
    const int j    = lane;

    // Membership bitmask for column j (bit i set iff (i,j) on the mask).
    const int sh = 63 - j;
    const unsigned long long mbits =
          (1ULL << j)
        | (0x7FFF000000000000ULL >> sh)
        | ((0x0000555500000000ULL >> sh) & 0x5555555555555555ULL)
        | ((0x0000000011111111ULL >> sh) & 0x1111111111111111ULL);

    const int tile0 = wid * T_PER_WAVE;

    float xv[T_PER_WAVE];
#pragma unroll
    for (int tt = 0; tt < T_PER_WAVE; ++tt)
        xv[tt] = x[(size_t)(tile0 + tt) * 64 + j];

#pragma unroll
    for (int tt = 0; tt < T_PER_WAVE; ++tt) {
        const int tile = tile0 + tt;
        float* __restrict__ bout = out + (size_t)tile * 4096;
        float* __restrict__ cout = bout + mapsz;
        const float xj = xv[tt];
        float r = xj;   // finite init: masked lanes never see -inf
#pragma unroll
        for (int i = 63; i >= 0; --i) {
            const float xi = __shfl(xv[tt], i, 64);      // uniform -> v_readlane
            const float xs = (j >= i) ? xi : -INFINITY;  // only fold once i <= j
            r = fmaxf(r, xs);
            const bool on  = (mbits >> i) & 1ULL;
            const float s  = on ? 0.5f : 0.0f;
            const float s2 = on ? 1.0f : 0.0f;
            __builtin_nontemporal_store(s * (xi + xj), bout + i * 64 + j);
            __builtin_nontemporal_store(s2 * r,        cout + i * 64 + j);
        }
        if ((tile & 511) == 0) {   // mask: one copy per batch (d==0 tile)
            float* __restrict__ mout = out + 2 * mapsz + (size_t)(tile >> 9) * 4096;
#pragma unroll
            for (int i = 0; i < 64; ++i)
                __builtin_nontemporal_store(((mbits >> i) & 1ULL) ? 1.0f : 0.0f,
                                            mout + i * 64 + j);
        }
    }
}

extern "C" void kernel_launch(void* const* d_in, const int* in_sizes, int n_in,
                              void* d_out, int out_size, void* d_ws, size_t ws_size,
                              hipStream_t stream) {
    const float* x = (const float*)d_in[0];
    float* out = (float*)d_out;
    const int N  = 64;
    const int BD = in_sizes[0] / N;                   // 8192 tiles
    const size_t mapsz = (size_t)BD * N * N;          // 33,554,432
    const int nwaves = BD / T_PER_WAVE;               // 4096
    sbc_kernel<<<dim3(nwaves / 4), dim3(256), 0, stream>>>(x, out, mapsz);
}

// Round 6
// 250.399 us; speedup vs baseline: 1.0496x; 1.0496x over previous
//
#include <hip/hip_runtime.h>

// Output layout (flat, reference return order), N=64, B=16, D=512:
//   [0,       mapsz)          boundary [B,D,N,N]
//   [mapsz, 2*mapsz)          content  [B,D,N,N]
//   [2*mapsz, 2*mapsz+B*N*N)  mask     [B,1,N,N] (0.0/1.0 f32)
//
// Identities (verified R1-R5): on member lines content[i,j] = max(x[i..j]),
// boundary[i,j] = 0.5*(x[i]+x[j]); the diagonal is the len=1 case of both.
//
// FINAL = R3 structure (best measured: 250.3 us). One wave per tile,
// lane = column j; running max over descending i (no gathers); membership
// as a per-lane 64-bit constant; no LDS, no barriers -> stores pipeline
// freely. Session findings: kernel-side variables (LDS vs registers,
// barriers, store width dword vs dwordx4, temporal vs nontemporal) all flat
// within noise — the timed window is dominated by the harness's in-graph
// 1.075 GB poison fill (~165 us @ 6.5 TB/s) + fixed overhead; the kernel's
// own 268.7 MB store stream is near its share of the budget.

#define T_PER_WAVE 2   // 8192 tiles / 2 = 4096 waves = 1024 blocks

__global__ __launch_bounds__(256) void sbc_kernel(const float* __restrict__ x,
                                                  float* __restrict__ out,
                                                  size_t mapsz) {
    const int lane = threadIdx.x & 63;               // column j
    const int wid  = blockIdx.x * 4 + (threadIdx.x >> 6);
    const int j    = lane;

    // Membership bitmask for column j: bit i set iff (i,j) is on the mask.
    //  diag: i==j
    //  g0: off=j-i in 1..15, any i
    //  g1: off odd in 17..31, i even
    //  g2: off%4==3 in 35..63, i%4==0
    const int sh = 63 - j;
    const unsigned long long mbits =
          (1ULL << j)
        | (0x7FFF000000000000ULL >> sh)
        | ((0x0000555500000000ULL >> sh) & 0x5555555555555555ULL)
        | ((0x0000000011111111ULL >> sh) & 0x1111111111111111ULL);

    const int tile0 = wid * T_PER_WAVE;

    // Preload this wave's tiles (256 B coalesced each), latencies overlapped.
    float xv[T_PER_WAVE];
#pragma unroll
    for (int tt = 0; tt < T_PER_WAVE; ++tt)
        xv[tt] = x[(size_t)(tile0 + tt) * 64 + j];

#pragma unroll
    for (int tt = 0; tt < T_PER_WAVE; ++tt) {
        const int tile = tile0 + tt;
        float* __restrict__ bout = out + (size_t)tile * 4096;
        float* __restrict__ cout = bout + mapsz;
        const float xj = xv[tt];
        float r = xj;   // finite init: masked lanes never see -inf
#pragma unroll
        for (int i = 63; i >= 0; --i) {
            const float xi = __shfl(xv[tt], i, 64);      // uniform -> v_readlane
            const float xs = (j >= i) ? xi : -INFINITY;  // fold only once i <= j
            r = fmaxf(r, xs);
            const bool on  = (mbits >> i) & 1ULL;
            const float s  = on ? 0.5f : 0.0f;
            const float s2 = on ? 1.0f : 0.0f;
            bout[i * 64 + j] = s * (xi + xj);
            cout[i * 64 + j] = s2 * r;
        }
        // mask: one copy per batch, owned by the tile with d==0
        if ((tile & 511) == 0) {
            float* __restrict__ mout = out + 2 * mapsz + (size_t)(tile >> 9) * 4096;
#pragma unroll
            for (int i = 0; i < 64; ++i)
                mout[i * 64 + j] = ((mbits >> i) & 1ULL) ? 1.0f : 0.0f;
        }
    }
}

extern "C" void kernel_launch(void* const* d_in, const int* in_sizes, int n_in,
                              void* d_out, int out_size, void* d_ws, size_t ws_size,
                              hipStream_t stream) {
    const float* x = (const float*)d_in[0];
    float* out = (float*)d_out;
    const int N  = 64;
    const int BD = in_sizes[0] / N;                   // 8192 tiles
    const size_t mapsz = (size_t)BD * N * N;          // 33,554,432
    const int nwaves = BD / T_PER_WAVE;               // 4096
    sbc_kernel<<<dim3(nwaves / 4), dim3(256), 0, stream>>>(x, out, mapsz);
}